// Round 1
// baseline (297.426 us; speedup 1.0000x reference)
//
#include <hip/hip_runtime.h>

#define N_EMB 4096
#define DIM 64
#define KS 8                  // K-split chunks
#define CHUNK (N_EMB / KS)    // 512 entries per chunk
#define BLK 256

// ---------------- kernel 1: codebook squared norms ----------------
__global__ void wnorm_kernel(const float* __restrict__ w, float* __restrict__ wnorm) {
    int k = blockIdx.x * blockDim.x + threadIdx.x;
    if (k >= N_EMB) return;
    const float4* wr = (const float4*)(w + (size_t)k * DIM);
    float s = 0.f;
#pragma unroll
    for (int j = 0; j < DIM / 4; ++j) {
        float4 v = wr[j];
        s += v.x * v.x + v.y * v.y + v.z * v.z + v.w * v.w;
    }
    wnorm[k] = s;
}

// ---------------- kernel 2: per-chunk partial argmin ----------------
// thread-per-row; each block handles 256 rows x one K-chunk of 512 entries.
// w / wnorm addresses are wave-uniform (k from loop counter) -> scalar loads.
__global__ void __launch_bounds__(BLK) partial_argmin(
    const float* __restrict__ x, const float* __restrict__ w,
    const float* __restrict__ wnorm,
    float* __restrict__ pdist, int* __restrict__ pidx, int nrows) {
    int row = blockIdx.x * blockDim.x + threadIdx.x;
    int chunk = blockIdx.y;
    if (row >= nrows) return;

    float xr[DIM];
    const float4* xp = (const float4*)(x + (size_t)row * DIM);
#pragma unroll
    for (int j = 0; j < DIM / 4; ++j) {
        float4 v = xp[j];
        xr[4 * j + 0] = v.x; xr[4 * j + 1] = v.y;
        xr[4 * j + 2] = v.z; xr[4 * j + 3] = v.w;
    }

    int k0 = chunk * CHUNK;
    float bestd = 3.4e38f;
    int besti = k0;
    for (int k = k0; k < k0 + CHUNK; k += 2) {
        const float* w0 = w + (size_t)k * DIM;
        const float* w1 = w0 + DIM;
        float a0 = 0.f, a1 = 0.f, b0 = 0.f, b1 = 0.f;
#pragma unroll
        for (int j = 0; j < DIM; j += 2) {
            a0 += xr[j] * w0[j];
            a1 += xr[j + 1] * w0[j + 1];
            b0 += xr[j] * w1[j];
            b1 += xr[j + 1] * w1[j + 1];
        }
        float d0 = wnorm[k] - 2.f * (a0 + a1);
        float d1 = wnorm[k + 1] - 2.f * (b0 + b1);
        // strict < in increasing k order == first-occurrence argmin
        if (d0 < bestd) { bestd = d0; besti = k; }
        if (d1 < bestd) { bestd = d1; besti = k + 1; }
    }
    pdist[(size_t)chunk * nrows + row] = bestd;
    pidx[(size_t)chunk * nrows + row] = besti;
}

// ---------------- kernel 3: reduce chunks, gather, write outputs ----------------
__global__ void finalize_kernel(
    const float* __restrict__ x, const float* __restrict__ w,
    const float* __restrict__ pdist, const int* __restrict__ pidx,
    float* __restrict__ qout, float* __restrict__ lout, int nrows) {
    int row = blockIdx.x * blockDim.x + threadIdx.x;
    if (row >= nrows) return;
    float bestd = 3.4e38f;
    int besti = 0;
#pragma unroll
    for (int c = 0; c < KS; ++c) {
        float d = pdist[(size_t)c * nrows + row];
        int i = pidx[(size_t)c * nrows + row];
        if (d < bestd) { bestd = d; besti = i; }  // chunks are in ascending k-range order
    }
    const float4* wr = (const float4*)(w + (size_t)besti * DIM);
    const float4* xp = (const float4*)(x + (size_t)row * DIM);
    float4* qp = (float4*)(qout + (size_t)row * DIM);
    float4* lp = (float4*)(lout + (size_t)row * DIM);
#pragma unroll
    for (int j = 0; j < DIM / 4; ++j) {
        float4 q = wr[j];
        float4 xv = xp[j];
        float4 df, qo, lo;
        df.x = q.x - xv.x; df.y = q.y - xv.y; df.z = q.z - xv.z; df.w = q.w - xv.w;
        // straight-through: out = x + (q - x), matches reference op order
        qo.x = xv.x + df.x; qo.y = xv.y + df.y; qo.z = xv.z + df.z; qo.w = xv.w + df.w;
        float sx = df.x * df.x, sy = df.y * df.y, sz = df.z * df.z, sw = df.w * df.w;
        lo.x = sx + 0.25f * sx; lo.y = sy + 0.25f * sy;
        lo.z = sz + 0.25f * sz; lo.w = sw + 0.25f * sw;
        qp[j] = qo;
        lp[j] = lo;
    }
}

// ---------------- fallback: fused single-pass (if ws too small) ----------------
__global__ void __launch_bounds__(BLK) fused_vq(
    const float* __restrict__ x, const float* __restrict__ w,
    const float* __restrict__ wnorm,
    float* __restrict__ qout, float* __restrict__ lout, int nrows) {
    int row = blockIdx.x * blockDim.x + threadIdx.x;
    if (row >= nrows) return;
    float xr[DIM];
    const float4* xp = (const float4*)(x + (size_t)row * DIM);
#pragma unroll
    for (int j = 0; j < DIM / 4; ++j) {
        float4 v = xp[j];
        xr[4 * j + 0] = v.x; xr[4 * j + 1] = v.y;
        xr[4 * j + 2] = v.z; xr[4 * j + 3] = v.w;
    }
    float bestd = 3.4e38f;
    int besti = 0;
    for (int k = 0; k < N_EMB; ++k) {
        const float* w0 = w + (size_t)k * DIM;
        float a0 = 0.f, a1 = 0.f;
#pragma unroll
        for (int j = 0; j < DIM; j += 2) {
            a0 += xr[j] * w0[j];
            a1 += xr[j + 1] * w0[j + 1];
        }
        float wn;
        if (wnorm) {
            wn = wnorm[k];
        } else {
            wn = 0.f;
#pragma unroll
            for (int j = 0; j < DIM; ++j) wn += w0[j] * w0[j];
        }
        float d = wn - 2.f * (a0 + a1);
        if (d < bestd) { bestd = d; besti = k; }
    }
    const float4* wr = (const float4*)(w + (size_t)besti * DIM);
    float4* qp = (float4*)(qout + (size_t)row * DIM);
    float4* lp = (float4*)(lout + (size_t)row * DIM);
#pragma unroll
    for (int j = 0; j < DIM / 4; ++j) {
        float4 q = wr[j];
        float4 xv = *(const float4*)(&xr[4 * j]);
        float4 df, qo, lo;
        df.x = q.x - xv.x; df.y = q.y - xv.y; df.z = q.z - xv.z; df.w = q.w - xv.w;
        qo.x = xv.x + df.x; qo.y = xv.y + df.y; qo.z = xv.z + df.z; qo.w = xv.w + df.w;
        float sx = df.x * df.x, sy = df.y * df.y, sz = df.z * df.z, sw = df.w * df.w;
        lo.x = sx + 0.25f * sx; lo.y = sy + 0.25f * sy;
        lo.z = sz + 0.25f * sz; lo.w = sw + 0.25f * sw;
        qp[j] = qo;
        lp[j] = lo;
    }
}

extern "C" void kernel_launch(void* const* d_in, const int* in_sizes, int n_in,
                              void* d_out, int out_size, void* d_ws, size_t ws_size,
                              hipStream_t stream) {
    const float* x = (const float*)d_in[0];   // [8,4096,64] f32
    const float* w = (const float*)d_in[1];   // [4096,64] f32
    const int nrows = in_sizes[0] / DIM;      // 32768
    float* qout = (float*)d_out;              // [nrows*DIM]
    float* lout = (float*)d_out + (size_t)nrows * DIM;

    // workspace layout: wnorm[N_EMB] f32 | pdist[KS*nrows] f32 | pidx[KS*nrows] i32
    const size_t wnorm_bytes = (size_t)N_EMB * sizeof(float);
    const size_t part_bytes = (size_t)KS * nrows * sizeof(float);
    const size_t need = wnorm_bytes + 2 * part_bytes;

    float* wnorm = (ws_size >= wnorm_bytes) ? (float*)d_ws : nullptr;
    if (wnorm) {
        wnorm_kernel<<<(N_EMB + BLK - 1) / BLK, BLK, 0, stream>>>(w, wnorm);
    }

    if (wnorm && ws_size >= need) {
        float* pdist = (float*)((char*)d_ws + wnorm_bytes);
        int* pidx = (int*)((char*)d_ws + wnorm_bytes + part_bytes);
        dim3 grid((nrows + BLK - 1) / BLK, KS);
        partial_argmin<<<grid, BLK, 0, stream>>>(x, w, wnorm, pdist, pidx, nrows);
        finalize_kernel<<<(nrows + BLK - 1) / BLK, BLK, 0, stream>>>(
            x, w, pdist, pidx, qout, lout, nrows);
    } else {
        fused_vq<<<(nrows + BLK - 1) / BLK, BLK, 0, stream>>>(
            x, w, wnorm, qout, lout, nrows);
    }
}

// Round 2
// 44.782 us; speedup vs baseline: 6.6416x; 6.6416x over previous
//
#include <hip/hip_runtime.h>

typedef __bf16 bf16x8 __attribute__((ext_vector_type(8)));
typedef float f32x16 __attribute__((ext_vector_type(16)));

#define N_EMB 4096
#define DIM 64
#define NCHUNK 128   // 4096 entries / 32 per chunk
#define RPB 64       // rows per block
#define NW 4         // waves per block (one K-quarter each)

// ---------------- helpers ----------------
__device__ __forceinline__ void upd(float& bst, int& pk, float d, int cd) {
    bool t = d < bst;
    bst = t ? d : bst;   // v_cmp + v_cndmask/min
    pk  = t ? cd : pk;   // v_cndmask (cd is wave-uniform -> SGPR operand)
}

// ---------------- prep: Wp = bf16(-2W) in A-fragment-linear layout, wnp = ||w||^2
// permuted into the 32x32 C-fragment register order ----------------
// A-frag (32x32x16): lane l holds row m = l%32, k = 8*(l/32)+e  ->
// Wp[(g*4+s)*64 + l][e] = -2*W[g*32 + l%32][s*16 + (l/32)*8 + e]
// C-frag: col = lane&31, row = (r&3) + 8*(r>>2) + 4*(lane>>5)   ->
// wnp[g*32 + hi*16 + r] = ||W[g*32 + (r&3)+8*(r>>2)+4*hi]||^2
__global__ void prep_kernel(const float* __restrict__ w, bf16x8* __restrict__ Wp,
                            float* __restrict__ wnp) {
    int id = blockIdx.x * blockDim.x + threadIdx.x;   // 8192 = 128 chunks * 64 lanes
    if (id >= NCHUNK * 64) return;
    int g = id >> 6, l = id & 63;
    int hi = l >> 5;
    const float* wr = w + (size_t)((g << 5) + (l & 31)) * DIM + hi * 8;
    float ss = 0.f;
#pragma unroll
    for (int s = 0; s < 4; ++s) {
        const float4* p = (const float4*)(wr + s * 16);
        float4 v0 = p[0], v1 = p[1];
        ss += v0.x*v0.x + v0.y*v0.y + v0.z*v0.z + v0.w*v0.w;
        ss += v1.x*v1.x + v1.y*v1.y + v1.z*v1.z + v1.w*v1.w;
        bf16x8 o;
        o[0]=(__bf16)(-2.f*v0.x); o[1]=(__bf16)(-2.f*v0.y);
        o[2]=(__bf16)(-2.f*v0.z); o[3]=(__bf16)(-2.f*v0.w);
        o[4]=(__bf16)(-2.f*v1.x); o[5]=(__bf16)(-2.f*v1.y);
        o[6]=(__bf16)(-2.f*v1.z); o[7]=(__bf16)(-2.f*v1.w);
        Wp[(g * 4 + s) * 64 + l] = o;
    }
    // each thread summed half the row (its hi part); combine with partner lane
    ss += __shfl_xor(ss, 32, 64);
    if (l < 32) {
        // invert row_in_chunk = (r&3) + 8*(r>>2) + 4*h  for row_in_chunk = l
        int h  = (l >> 2) & 1;
        int rr = l - (h << 2);                   // (r&3) + 8*(r>>2)
        int r  = (rr & 7) + ((rr >> 3) << 2);
        wnp[(g << 5) + (h << 4) + r] = ss;
    }
}

// ---------------- main ----------------
__device__ __forceinline__ void load_xfrag(bf16x8* dst, const float* __restrict__ x,
                                           int row, int hi) {
#pragma unroll
    for (int s = 0; s < 4; ++s) {
        // B-frag (16x32): lane holds col n = l%32, k = 8*(l/32)+e ->
        // x[row = n][d = s*16 + hi*8 + e], 8 contiguous f32 -> bf16
        const float4* p = (const float4*)(x + (size_t)row * DIM + s * 16 + hi * 8);
        float4 v0 = p[0], v1 = p[1];
        bf16x8 v;
        v[0]=(__bf16)v0.x; v[1]=(__bf16)v0.y; v[2]=(__bf16)v0.z; v[3]=(__bf16)v0.w;
        v[4]=(__bf16)v1.x; v[5]=(__bf16)v1.y; v[6]=(__bf16)v1.z; v[7]=(__bf16)v1.w;
        dst[s] = v;
    }
}

__device__ __forceinline__ void load_afrag(bf16x8* a, const bf16x8* __restrict__ Wp,
                                           int g, int lane) {
    const bf16x8* ap = Wp + (size_t)g * 256 + lane;  // coalesced dwordx4, 1KB/wave
    a[0] = ap[0]; a[1] = ap[64]; a[2] = ap[128]; a[3] = ap[192];
}

__device__ __forceinline__ void compute_chunk(
    const bf16x8* a, const bf16x8* xb0, const bf16x8* xb1,
    const float* __restrict__ wnp, int g, int hi,
    float& best0, int& pack0, float& best1, int& pack1) {
    // fold ||w||^2 into the accumulator init: D = wn - 2*x.w  (W pre-scaled by -2)
    const f32x16* wp = (const f32x16*)(wnp + (g << 5) + (hi << 4));
    f32x16 acc0 = *wp;      // 4x global_load_dwordx4, broadcast (L1-hot)
    f32x16 acc1 = acc0;
#pragma unroll
    for (int s = 0; s < 4; ++s) {   // K = 64 = 4 x 16, accumulate in place
        acc0 = __builtin_amdgcn_mfma_f32_32x32x16_bf16(a[s], xb0[s], acc0, 0, 0, 0);
        acc1 = __builtin_amdgcn_mfma_f32_32x32x16_bf16(a[s], xb1[s], acc1, 0, 0, 0);
    }
#pragma unroll
    for (int r = 0; r < 16; ++r) {
        int cd = (g << 4) | r;      // wave-uniform candidate id (chunk, reg)
        upd(best0, pack0, acc0[r], cd);
        upd(best1, pack1, acc1[r], cd);
    }
}

__global__ void __launch_bounds__(256) vq_main(
    const float* __restrict__ x, const float* __restrict__ w,
    const bf16x8* __restrict__ Wp, const float* __restrict__ wnp,
    float* __restrict__ qout, float* __restrict__ lout, int nrows) {
    __shared__ float pbest[NW][RPB];
    __shared__ int   ppack[NW][RPB];
    __shared__ int   spack[RPB];

    const int tid  = threadIdx.x;
    const int wv   = tid >> 6;        // wave id = K-quarter
    const int lane = tid & 63;
    const int li   = lane & 31;
    const int hi   = lane >> 5;
    const int rowBase = blockIdx.x * RPB;

    // x fragments for this block's 64 rows: 2 col-sets of 32, held in regs
    bf16x8 xb0[4], xb1[4];
    {
        int r0 = rowBase + li;       if (r0 >= nrows) r0 = nrows - 1;
        int r1 = rowBase + 32 + li;  if (r1 >= nrows) r1 = nrows - 1;
        load_xfrag(xb0, x, r0, hi);
        load_xfrag(xb1, x, r1, hi);
    }

    float best0 = 3.4e38f, best1 = 3.4e38f;
    int pack0 = 0, pack1 = 0;
    const int gB = wv * 32;          // this wave's 32 chunks (1024 entries)

    bf16x8 aA[4], aB[4];
    load_afrag(aA, Wp, gB, lane);
    for (int c = 0; c < 32; c += 2) {            // reg-double-buffered prefetch
        load_afrag(aB, Wp, gB + c + 1, lane);
        compute_chunk(aA, xb0, xb1, wnp, gB + c, hi, best0, pack0, best1, pack1);
        if (c + 2 < 32) load_afrag(aA, Wp, gB + c + 2, lane);
        compute_chunk(aB, xb0, xb1, wnp, gB + c + 1, hi, best0, pack0, best1, pack1);
    }

    // combine hi halves (lanes l and l+32 hold complementary 16 entries per chunk)
    {
        float ob = __shfl_xor(best0, 32, 64);
        int   op = __shfl_xor(pack0, 32, 64);
        bool tk = hi ? (ob <= best0) : (ob < best0);   // tie -> hi=0 wins, consistent
        best0 = tk ? ob : best0;
        pack0 = ((tk ? op : pack0) << 1) | (tk ? (hi ^ 1) : hi);
    }
    {
        float ob = __shfl_xor(best1, 32, 64);
        int   op = __shfl_xor(pack1, 32, 64);
        bool tk = hi ? (ob <= best1) : (ob < best1);
        best1 = tk ? ob : best1;
        pack1 = ((tk ? op : pack1) << 1) | (tk ? (hi ^ 1) : hi);
    }
    if (lane < 32) {
        pbest[wv][li]      = best0;  ppack[wv][li]      = pack0;
        pbest[wv][32 + li] = best1;  ppack[wv][32 + li] = pack1;
    }
    __syncthreads();

    // reduce the 4 K-quarters (ascending entry ranges -> strict < keeps first occurrence)
    if (tid < RPB) {
        float bv = pbest[0][tid];
        int   bp = ppack[0][tid];
#pragma unroll
        for (int q = 1; q < NW; ++q) {
            float v = pbest[q][tid];
            if (v < bv) { bv = v; bp = ppack[q][tid]; }
        }
        spack[tid] = bp;
    }
    __syncthreads();

    // fused epilogue: gather exact f32 codebook row, write quantized + loss
    {
        int rl = tid >> 2, part = tid & 3;
        int row = rowBase + rl;
        if (row < nrows) {
            int p   = spack[rl];
            int h2  = p & 1;
            int pr  = p >> 1;
            int r   = pr & 15;
            int g   = pr >> 4;
            int entry = (g << 5) + (r & 3) + ((r >> 2) << 3) + (h2 << 2);
            const float4* wr = (const float4*)(w + (size_t)entry * DIM + part * 16);
            const float4* xr = (const float4*)(x + (size_t)row * DIM + part * 16);
            float4* qo = (float4*)(qout + (size_t)row * DIM + part * 16);
            float4* lo = (float4*)(lout + (size_t)row * DIM + part * 16);
#pragma unroll
            for (int j = 0; j < 4; ++j) {
                float4 q = wr[j], xv = xr[j], df, qv, lv;
                df.x = q.x - xv.x; df.y = q.y - xv.y; df.z = q.z - xv.z; df.w = q.w - xv.w;
                qv.x = xv.x + df.x; qv.y = xv.y + df.y; qv.z = xv.z + df.z; qv.w = xv.w + df.w;
                float sx = df.x*df.x, sy = df.y*df.y, sz = df.z*df.z, sw = df.w*df.w;
                lv.x = sx + 0.25f*sx; lv.y = sy + 0.25f*sy;
                lv.z = sz + 0.25f*sz; lv.w = sw + 0.25f*sw;
                qo[j] = qv;
                lo[j] = lv;
            }
        }
    }
}

extern "C" void kernel_launch(void* const* d_in, const int* in_sizes, int n_in,
                              void* d_out, int out_size, void* d_ws, size_t ws_size,
                              hipStream_t stream) {
    const float* x = (const float*)d_in[0];   // [8,4096,64] f32
    const float* w = (const float*)d_in[1];   // [4096,64] f32
    const int nrows = in_sizes[0] / DIM;      // 32768
    float* qout = (float*)d_out;
    float* lout = (float*)d_out + (size_t)nrows * DIM;

    // workspace: Wp bf16 fragment-linear (512 KB) | wnp f32 permuted (16 KB)
    bf16x8* Wp  = (bf16x8*)d_ws;
    float*  wnp = (float*)((char*)d_ws + (size_t)N_EMB * DIM * 2);

    prep_kernel<<<(NCHUNK * 64 + 255) / 256, 256, 0, stream>>>(w, Wp, wnp);

    int nb = (nrows + RPB - 1) / RPB;         // 512 blocks, 4 waves each
    vq_main<<<nb, 256, 0, stream>>>(x, w, Wp, wnp, qout, lout, nrows);
}

// Round 3
// 43.556 us; speedup vs baseline: 6.8286x; 1.0282x over previous
//
#include <hip/hip_runtime.h>

typedef __bf16 bf16x8 __attribute__((ext_vector_type(8)));
typedef float f32x16 __attribute__((ext_vector_type(16)));

#define N_EMB 4096
#define DIM 64
#define NCHUNK 128            // 4096 entries / 32 per chunk
#define RPB 64                // rows per block
#define NW 8                  // waves per block (one K-eighth each)
#define CPW (NCHUNK / NW)     // 16 chunks per wave

// ---------------- helpers ----------------
__device__ __forceinline__ void upd(float& bst, int& pk, float d, int cd) {
    bool t = d < bst;
    bst = t ? d : bst;   // v_cmp + v_cndmask
    pk  = t ? cd : pk;   // v_cndmask (cd wave-uniform -> SGPR operand)
}

// ---------------- prep: Wp = bf16(-2W) in A-fragment-linear layout, wnp = ||w||^2
// permuted into the 32x32 C-fragment register order ----------------
// A-frag (32x32x16): lane l holds row m = l%32, k = 8*(l/32)+e  ->
// Wp[(g*4+s)*64 + l][e] = -2*W[g*32 + l%32][s*16 + (l/32)*8 + e]
// C-frag: col = lane&31, row = (r&3) + 8*(r>>2) + 4*(lane>>5)   ->
// wnp[g*32 + hi*16 + r] = ||W[g*32 + (r&3)+8*(r>>2)+4*hi]||^2
__global__ void prep_kernel(const float* __restrict__ w, bf16x8* __restrict__ Wp,
                            float* __restrict__ wnp) {
    int id = blockIdx.x * blockDim.x + threadIdx.x;   // 8192 = 128 chunks * 64 lanes
    if (id >= NCHUNK * 64) return;
    int g = id >> 6, l = id & 63;
    int hi = l >> 5;
    const float* wr = w + (size_t)((g << 5) + (l & 31)) * DIM + hi * 8;
    float ss = 0.f;
#pragma unroll
    for (int s = 0; s < 4; ++s) {
        const float4* p = (const float4*)(wr + s * 16);
        float4 v0 = p[0], v1 = p[1];
        ss += v0.x*v0.x + v0.y*v0.y + v0.z*v0.z + v0.w*v0.w;
        ss += v1.x*v1.x + v1.y*v1.y + v1.z*v1.z + v1.w*v1.w;
        bf16x8 o;
        o[0]=(__bf16)(-2.f*v0.x); o[1]=(__bf16)(-2.f*v0.y);
        o[2]=(__bf16)(-2.f*v0.z); o[3]=(__bf16)(-2.f*v0.w);
        o[4]=(__bf16)(-2.f*v1.x); o[5]=(__bf16)(-2.f*v1.y);
        o[6]=(__bf16)(-2.f*v1.z); o[7]=(__bf16)(-2.f*v1.w);
        Wp[(g * 4 + s) * 64 + l] = o;
    }
    // each thread summed half the row (its hi part); combine with partner lane
    ss += __shfl_xor(ss, 32, 64);
    if (l < 32) {
        // invert row_in_chunk = (r&3) + 8*(r>>2) + 4*h  for row_in_chunk = l
        int h  = (l >> 2) & 1;
        int rr = l - (h << 2);                   // (r&3) + 8*(r>>2)
        int r  = (rr & 7) + ((rr >> 3) << 2);
        wnp[(g << 5) + (h << 4) + r] = ss;
    }
}

// ---------------- main ----------------
__device__ __forceinline__ void load_xfrag(bf16x8* dst, const float* __restrict__ x,
                                           int row, int hi) {
#pragma unroll
    for (int s = 0; s < 4; ++s) {
        // B-frag (16x32): lane holds col n = l%32, k = 8*(l/32)+e ->
        // x[row = n][d = s*16 + hi*8 + e], 8 contiguous f32 -> bf16
        const float4* p = (const float4*)(x + (size_t)row * DIM + s * 16 + hi * 8);
        float4 v0 = p[0], v1 = p[1];
        bf16x8 v;
        v[0]=(__bf16)v0.x; v[1]=(__bf16)v0.y; v[2]=(__bf16)v0.z; v[3]=(__bf16)v0.w;
        v[4]=(__bf16)v1.x; v[5]=(__bf16)v1.y; v[6]=(__bf16)v1.z; v[7]=(__bf16)v1.w;
        dst[s] = v;
    }
}

__device__ __forceinline__ void load_afrag(bf16x8* a, const bf16x8* __restrict__ Wp,
                                           int g, int lane) {
    const bf16x8* ap = Wp + (size_t)g * 256 + lane;  // coalesced dwordx4, 1KB/wave
    a[0] = ap[0]; a[1] = ap[64]; a[2] = ap[128]; a[3] = ap[192];
}

__device__ __forceinline__ void compute_chunk(
    const bf16x8* a, const bf16x8* xb0, const bf16x8* xb1,
    const float* __restrict__ wnp, int g, int hi,
    float* best0, int* pack0, float* best1, int* pack1) {
    // fold ||w||^2 into the accumulator init: D = wn - 2*x.w  (W pre-scaled by -2)
    const f32x16* wp = (const f32x16*)(wnp + (g << 5) + (hi << 4));
    f32x16 acc0 = *wp;      // 4x global_load_dwordx4, broadcast (L1-hot)
    f32x16 acc1 = acc0;
#pragma unroll
    for (int s = 0; s < 4; ++s) {   // K = 64 = 4 x 16, accumulate in place
        acc0 = __builtin_amdgcn_mfma_f32_32x32x16_bf16(a[s], xb0[s], acc0, 0, 0, 0);
        acc1 = __builtin_amdgcn_mfma_f32_32x32x16_bf16(a[s], xb1[s], acc1, 0, 0, 0);
    }
    // 4 independent argmin chains per acc (chain = r&3) -> serial depth 8, not 32
#pragma unroll
    for (int r = 0; r < 16; ++r) {
        int cd = (g << 4) | r;      // wave-uniform candidate id (chunk, reg)
        upd(best0[r & 3], pack0[r & 3], acc0[r], cd);
        upd(best1[r & 3], pack1[r & 3], acc1[r], cd);
    }
}

__global__ void __launch_bounds__(512) vq_main(
    const float* __restrict__ x, const float* __restrict__ w,
    const bf16x8* __restrict__ Wp, const float* __restrict__ wnp,
    float* __restrict__ qout, float* __restrict__ lout, int nrows) {
    __shared__ float pbest[NW][RPB];
    __shared__ int   ppack[NW][RPB];
    __shared__ int   spack[RPB];

    const int tid  = threadIdx.x;
    const int wv   = tid >> 6;        // wave id = K-eighth
    const int lane = tid & 63;
    const int li   = lane & 31;
    const int hi   = lane >> 5;
    const int rowBase = blockIdx.x * RPB;

    // x fragments for this block's 64 rows: 2 col-sets of 32, held in regs
    bf16x8 xb0[4], xb1[4];
    {
        int r0 = rowBase + li;       if (r0 >= nrows) r0 = nrows - 1;
        int r1 = rowBase + 32 + li;  if (r1 >= nrows) r1 = nrows - 1;
        load_xfrag(xb0, x, r0, hi);
        load_xfrag(xb1, x, r1, hi);
    }

    float best0[4], best1[4];
    int   pack0[4], pack1[4];
#pragma unroll
    for (int j = 0; j < 4; ++j) {
        best0[j] = 3.4e38f; best1[j] = 3.4e38f;
        pack0[j] = 0;       pack1[j] = 0;
    }
    const int gB = wv * CPW;          // this wave's 16 chunks (512 entries)

    bf16x8 aA[4], aB[4];
    load_afrag(aA, Wp, gB, lane);
    for (int c = 0; c < CPW; c += 2) {            // reg-double-buffered prefetch
        load_afrag(aB, Wp, gB + c + 1, lane);
        compute_chunk(aA, xb0, xb1, wnp, gB + c, hi, best0, pack0, best1, pack1);
        if (c + 2 < CPW) load_afrag(aA, Wp, gB + c + 2, lane);
        compute_chunk(aB, xb0, xb1, wnp, gB + c + 1, hi, best0, pack0, best1, pack1);
    }

    // merge the 4 chains (strict < favors lower chain = lower row within same hi)
    float b0 = best0[0], b1 = best1[0];
    int   p0 = pack0[0], p1 = pack1[0];
#pragma unroll
    for (int j = 1; j < 4; ++j) {
        if (best0[j] < b0) { b0 = best0[j]; p0 = pack0[j]; }
        if (best1[j] < b1) { b1 = best1[j]; p1 = pack1[j]; }
    }

    // combine hi halves (lanes l and l+32 hold complementary 16 entries per chunk)
    {
        float ob = __shfl_xor(b0, 32, 64);
        int   op = __shfl_xor(p0, 32, 64);
        bool tk = hi ? (ob <= b0) : (ob < b0);   // tie -> hi=0 wins, consistent
        b0 = tk ? ob : b0;
        p0 = ((tk ? op : p0) << 1) | (tk ? (hi ^ 1) : hi);
    }
    {
        float ob = __shfl_xor(b1, 32, 64);
        int   op = __shfl_xor(p1, 32, 64);
        bool tk = hi ? (ob <= b1) : (ob < b1);
        b1 = tk ? ob : b1;
        p1 = ((tk ? op : p1) << 1) | (tk ? (hi ^ 1) : hi);
    }
    if (lane < 32) {
        pbest[wv][li]      = b0;  ppack[wv][li]      = p0;
        pbest[wv][32 + li] = b1;  ppack[wv][32 + li] = p1;
    }
    __syncthreads();

    // reduce the 8 K-eighths (ascending entry ranges -> strict < keeps first occurrence)
    if (tid < RPB) {
        float bv = pbest[0][tid];
        int   bp = ppack[0][tid];
#pragma unroll
        for (int q = 1; q < NW; ++q) {
            float v = pbest[q][tid];
            if (v < bv) { bv = v; bp = ppack[q][tid]; }
        }
        spack[tid] = bp;
    }
    __syncthreads();

    // fused epilogue: gather exact f32 codebook row, write quantized + loss
    {
        int rl = tid >> 3, part = tid & 7;       // 512 threads = 64 rows x 8 parts
        int row = rowBase + rl;
        if (row < nrows) {
            int p   = spack[rl];
            int h2  = p & 1;
            int pr  = p >> 1;
            int r   = pr & 15;
            int g   = pr >> 4;
            int entry = (g << 5) + (r & 3) + ((r >> 2) << 3) + (h2 << 2);
            const float4* wr = (const float4*)(w + (size_t)entry * DIM + part * 8);
            const float4* xr = (const float4*)(x + (size_t)row * DIM + part * 8);
            float4* qo = (float4*)(qout + (size_t)row * DIM + part * 8);
            float4* lo = (float4*)(lout + (size_t)row * DIM + part * 8);
#pragma unroll
            for (int j = 0; j < 2; ++j) {
                float4 q = wr[j], xv = xr[j], df, qv, lv;
                df.x = q.x - xv.x; df.y = q.y - xv.y; df.z = q.z - xv.z; df.w = q.w - xv.w;
                qv.x = xv.x + df.x; qv.y = xv.y + df.y; qv.z = xv.z + df.z; qv.w = xv.w + df.w;
                float sx = df.x*df.x, sy = df.y*df.y, sz = df.z*df.z, sw = df.w*df.w;
                lv.x = sx + 0.25f*sx; lv.y = sy + 0.25f*sy;
                lv.z = sz + 0.25f*sz; lv.w = sw + 0.25f*sw;
                qo[j] = qv;
                lo[j] = lv;
            }
        }
    }
}

extern "C" void kernel_launch(void* const* d_in, const int* in_sizes, int n_in,
                              void* d_out, int out_size, void* d_ws, size_t ws_size,
                              hipStream_t stream) {
    const float* x = (const float*)d_in[0];   // [8,4096,64] f32
    const float* w = (const float*)d_in[1];   // [4096,64] f32
    const int nrows = in_sizes[0] / DIM;      // 32768
    float* qout = (float*)d_out;
    float* lout = (float*)d_out + (size_t)nrows * DIM;

    // workspace: Wp bf16 fragment-linear (512 KB) | wnp f32 permuted (16 KB)
    bf16x8* Wp  = (bf16x8*)d_ws;
    float*  wnp = (float*)((char*)d_ws + (size_t)N_EMB * DIM * 2);

    prep_kernel<<<(NCHUNK * 64 + 255) / 256, 256, 0, stream>>>(w, Wp, wnp);

    int nb = (nrows + RPB - 1) / RPB;         // 512 blocks, 8 waves each
    vq_main<<<nb, 512, 0, stream>>>(x, w, Wp, wnp, qout, lout, nrows);
}

// Round 4
// 39.490 us; speedup vs baseline: 7.5317x; 1.1030x over previous
//
#include <hip/hip_runtime.h>

typedef __bf16 bf16x8 __attribute__((ext_vector_type(8)));
typedef float f32x16 __attribute__((ext_vector_type(16)));

#define N_EMB 4096
#define DIM 64
#define NCHUNK 128            // 4096 entries / 32 per chunk
#define RPB 128               // rows per block (4 rowsets of 32)
#define NW 8                  // waves per block (chunk-split)
#define CPW (NCHUNK / NW)     // 16 chunks per wave
#define NRS 4                 // rowsets per wave

// ---------------- prep: Wp = bf16(-2W) in A-fragment-linear layout, wnp = ||w||^2
// permuted into the 32x32 C-fragment register order (verified rounds 2-3) ----------------
// A-frag (32x32x16): lane l holds row m = l%32, k = 8*(l/32)+e  ->
// Wp[(g*4+s)*64 + l][e] = -2*W[g*32 + l%32][s*16 + (l/32)*8 + e]
// C-frag: col = lane&31, row = (r&3) + 8*(r>>2) + 4*(lane>>5)   ->
// wnp[g*32 + hi*16 + r] = ||W[g*32 + (r&3)+8*(r>>2)+4*hi]||^2
__global__ void prep_kernel(const float* __restrict__ w, bf16x8* __restrict__ Wp,
                            float* __restrict__ wnp) {
    int id = blockIdx.x * blockDim.x + threadIdx.x;   // 8192 = 128 chunks * 64 lanes
    if (id >= NCHUNK * 64) return;
    int g = id >> 6, l = id & 63;
    int hi = l >> 5;
    const float* wr = w + (size_t)((g << 5) + (l & 31)) * DIM + hi * 8;
    float ss = 0.f;
#pragma unroll
    for (int s = 0; s < 4; ++s) {
        const float4* p = (const float4*)(wr + s * 16);
        float4 v0 = p[0], v1 = p[1];
        ss += v0.x*v0.x + v0.y*v0.y + v0.z*v0.z + v0.w*v0.w;
        ss += v1.x*v1.x + v1.y*v1.y + v1.z*v1.z + v1.w*v1.w;
        bf16x8 o;
        o[0]=(__bf16)(-2.f*v0.x); o[1]=(__bf16)(-2.f*v0.y);
        o[2]=(__bf16)(-2.f*v0.z); o[3]=(__bf16)(-2.f*v0.w);
        o[4]=(__bf16)(-2.f*v1.x); o[5]=(__bf16)(-2.f*v1.y);
        o[6]=(__bf16)(-2.f*v1.z); o[7]=(__bf16)(-2.f*v1.w);
        Wp[(g * 4 + s) * 64 + l] = o;
    }
    ss += __shfl_xor(ss, 32, 64);
    if (l < 32) {
        int h  = (l >> 2) & 1;
        int rr = l - (h << 2);
        int r  = (rr & 7) + ((rr >> 3) << 2);
        wnp[(g << 5) + (h << 4) + r] = ss;
    }
}

// ---------------- main ----------------
__device__ __forceinline__ void load_xfrag(bf16x8* dst, const float* __restrict__ x,
                                           int row, int hi) {
#pragma unroll
    for (int s = 0; s < 4; ++s) {
        const float4* p = (const float4*)(x + (size_t)row * DIM + s * 16 + hi * 8);
        float4 v0 = p[0], v1 = p[1];
        bf16x8 v;
        v[0]=(__bf16)v0.x; v[1]=(__bf16)v0.y; v[2]=(__bf16)v0.z; v[3]=(__bf16)v0.w;
        v[4]=(__bf16)v1.x; v[5]=(__bf16)v1.y; v[6]=(__bf16)v1.z; v[7]=(__bf16)v1.w;
        dst[s] = v;
    }
}

// prefetch one chunk's A-fragments AND its wnp C-fragment together
__device__ __forceinline__ void load_bufs(bf16x8* a, f32x16* wf,
        const bf16x8* __restrict__ Wp, const float* __restrict__ wnp,
        int g, int lane, int hi) {
    const bf16x8* ap = Wp + (size_t)g * 256 + lane;   // coalesced dwordx4
    a[0] = ap[0]; a[1] = ap[64]; a[2] = ap[128]; a[3] = ap[192];
    *wf = *(const f32x16*)(wnp + (g << 5) + (hi << 4));  // broadcast, L1-hot
}

__device__ __forceinline__ void compute_chunk(
        const bf16x8* a, const f32x16& wf, const bf16x8 xb[NRS][4],
        float pb[NRS][16], int ctag) {
    const uint32_t cu = (uint32_t)ctag;      // chunk tag, 4 bits
#pragma unroll
    for (int rs = 0; rs < NRS; ++rs) {
        // C-init directly from the prefetched ||w||^2 fragment: zero copies
        f32x16 acc = __builtin_amdgcn_mfma_f32_32x32x16_bf16(a[0], xb[rs][0], wf, 0, 0, 0);
        acc = __builtin_amdgcn_mfma_f32_32x32x16_bf16(a[1], xb[rs][1], acc, 0, 0, 0);
        acc = __builtin_amdgcn_mfma_f32_32x32x16_bf16(a[2], xb[rs][2], acc, 0, 0, 0);
        acc = __builtin_amdgcn_mfma_f32_32x32x16_bf16(a[3], xb[rs][3], acc, 0, 0, 0);
        // packed argmin: clear low 4 mantissa bits, tag with chunk id ->
        // v_and_or_b32 + v_min_f32 = 2 VALU/entry, 16 independent positional chains
#pragma unroll
        for (int r = 0; r < 16; ++r) {
            uint32_t t = (__builtin_bit_cast(uint32_t, acc[r]) & 0xFFFFFFF0u) | cu;
            pb[rs][r] = fminf(pb[rs][r], __builtin_bit_cast(float, t));
        }
    }
}

__global__ void __launch_bounds__(512, 2) vq_main(
    const float* __restrict__ x, const float* __restrict__ w,
    const bf16x8* __restrict__ Wp, const float* __restrict__ wnp,
    float* __restrict__ qout, float* __restrict__ lout, int nrows) {
    __shared__ float pbest[NW][RPB];
    __shared__ int   sidx[RPB];

    const int tid  = threadIdx.x;
    const int wv   = tid >> 6;
    const int lane = tid & 63;
    const int li   = lane & 31;
    const int hi   = lane >> 5;
    const int rowBase = blockIdx.x * RPB;

    // x fragments: 4 rowsets of 32 rows, held in registers (64 VGPRs)
    bf16x8 xb[NRS][4];
#pragma unroll
    for (int rs = 0; rs < NRS; ++rs) {
        int r0 = rowBase + rs * 32 + li;
        if (r0 >= nrows) r0 = nrows - 1;
        load_xfrag(xb[rs], x, r0, hi);
    }

    float pb[NRS][16];
#pragma unroll
    for (int rs = 0; rs < NRS; ++rs)
#pragma unroll
        for (int r = 0; r < 16; ++r) pb[rs][r] = 3.4e38f;

    const int gB = wv * CPW;

    // double-buffered prefetch of A-frags + wnp C-frag: no load on critical path
    bf16x8 aA[4], aB[4];
    f32x16 wA, wB;
    load_bufs(aA, &wA, Wp, wnp, gB, lane, hi);
    for (int c = 0; c < CPW; c += 2) {
        load_bufs(aB, &wB, Wp, wnp, gB + c + 1, lane, hi);
        compute_chunk(aA, wA, xb, pb, c);
        if (c + 2 < CPW) load_bufs(aA, &wA, Wp, wnp, gB + c + 2, lane, hi);
        compute_chunk(aB, wB, xb, pb, c + 1);
    }

    // post-loop index reconstruction (once per wave, ~amortized to nothing)
#pragma unroll
    for (int rs = 0; rs < NRS; ++rs) {
        float bv = pb[rs][0];
        int   br = 0;
#pragma unroll
        for (int r = 1; r < 16; ++r) {
            bool t = pb[rs][r] < bv;
            bv = t ? pb[rs][r] : bv;
            br = t ? r : br;
        }
        uint32_t bits = __builtin_bit_cast(uint32_t, bv);
        uint32_t ctag = bits & 0xFu;
        uint32_t cr   = (uint32_t)((br & 3) + ((br >> 2) << 3));
        uint32_t entry = (((uint32_t)gB + ctag) << 5) + cr + ((uint32_t)hi << 2);
        // repack with full 12-bit entry id for the pure-min merges
        float pv = __builtin_bit_cast(float, (bits & 0xFFFFF000u) | entry);
        // hi-half merge: lanes l and l+32 hold complementary entries
        float ov = __shfl_xor(pv, 32, 64);
        pv = fminf(pv, ov);
        if (lane < 32) pbest[wv][rs * 32 + li] = pv;
    }
    __syncthreads();

    // cross-wave merge: 8 chunk-ranges -> global argmin per row (pure v_min)
    if (tid < RPB) {
        float m = pbest[0][tid];
#pragma unroll
        for (int q = 1; q < NW; ++q) m = fminf(m, pbest[q][tid]);
        sidx[tid] = (int)(__builtin_bit_cast(uint32_t, m) & 0xFFFu);
    }
    __syncthreads();

    // fused epilogue: gather exact f32 codebook row, write quantized + loss
    {
        int rl = tid >> 2, part = tid & 3;    // 512 threads = 128 rows x 4 parts
        int row = rowBase + rl;
        if (row < nrows) {
            int entry = sidx[rl];
            const float4* wr = (const float4*)(w + (size_t)entry * DIM + part * 16);
            const float4* xr = (const float4*)(x + (size_t)row * DIM + part * 16);
            float4* qo = (float4*)(qout + (size_t)row * DIM + part * 16);
            float4* lo = (float4*)(lout + (size_t)row * DIM + part * 16);
#pragma unroll
            for (int j = 0; j < 4; ++j) {
                float4 q = wr[j], xv = xr[j], df, qv, lv;
                df.x = q.x - xv.x; df.y = q.y - xv.y; df.z = q.z - xv.z; df.w = q.w - xv.w;
                qv.x = xv.x + df.x; qv.y = xv.y + df.y; qv.z = xv.z + df.z; qv.w = xv.w + df.w;
                float sx = df.x*df.x, sy = df.y*df.y, sz = df.z*df.z, sw = df.w*df.w;
                lv.x = sx + 0.25f*sx; lv.y = sy + 0.25f*sy;
                lv.z = sz + 0.25f*sz; lv.w = sw + 0.25f*sw;
                qo[j] = qv;
                lo[j] = lv;
            }
        }
    }
}

extern "C" void kernel_launch(void* const* d_in, const int* in_sizes, int n_in,
                              void* d_out, int out_size, void* d_ws, size_t ws_size,
                              hipStream_t stream) {
    const float* x = (const float*)d_in[0];   // [8,4096,64] f32
    const float* w = (const float*)d_in[1];   // [4096,64] f32
    const int nrows = in_sizes[0] / DIM;      // 32768
    float* qout = (float*)d_out;
    float* lout = (float*)d_out + (size_t)nrows * DIM;

    // workspace: Wp bf16 fragment-linear (512 KB) | wnp f32 permuted (16 KB)
    bf16x8* Wp  = (bf16x8*)d_ws;
    float*  wnp = (float*)((char*)d_ws + (size_t)N_EMB * DIM * 2);

    prep_kernel<<<(NCHUNK * 64 + 255) / 256, 256, 0, stream>>>(w, Wp, wnp);

    int nb = (nrows + RPB - 1) / RPB;         // 256 blocks, 8 waves each
    vq_main<<<nb, 512, 0, stream>>>(x, w, Wp, wnp, qout, lout, nrows);
}